// Round 1
// baseline (332.433 us; speedup 1.0000x reference)
//
#include <hip/hip_runtime.h>

#define RANK 12
#define RES 192
#define NHW (RES * RES)
#define NF 36
#define ODIM 32

// ---------------------------------------------------------------------------
// Pre-pass: transpose the three planes from [R][H][W] to [H][W][R] so one
// bilinear tap reads 12 contiguous floats (3x float4) instead of 12 scattered
// 4B gathers 144KB apart.
// ---------------------------------------------------------------------------
__global__ __launch_bounds__(256) void vme_transpose(const float* __restrict__ a,
                                                     const float* __restrict__ b,
                                                     const float* __restrict__ c,
                                                     float* __restrict__ t) {
    int idx = blockIdx.x * 256 + threadIdx.x;
    if (idx >= 3 * NHW) return;
    int p = idx / NHW;
    int yx = idx - p * NHW;
    const float* src = (p == 0) ? a : (p == 1) ? b : c;
    float* dst = t + ((size_t)p * NHW + (size_t)yx) * RANK;
#pragma unroll
    for (int r = 0; r < RANK; ++r) dst[r] = src[(size_t)r * NHW + yx];
}

// ---------------------------------------------------------------------------
// Main kernel: one thread per point.
//   TR = true : sample from transposed planes tp [3][H][W][12] (float4 loads)
//   TR = false: sample from original planes (correct fallback if ws too small)
// ---------------------------------------------------------------------------
template <bool TR>
__global__ __launch_bounds__(256) void vme_main(const float* __restrict__ xyz,
                                                const float* __restrict__ pa,
                                                const float* __restrict__ pb,
                                                const float* __restrict__ pc,
                                                const float* __restrict__ tp,
                                                const float* __restrict__ w,
                                                float* __restrict__ out,
                                                int n) {
    int i = blockIdx.x * 256 + threadIdx.x;
    if (i >= n) return;

    float px = xyz[3 * (size_t)i + 0];
    float py = xyz[3 * (size_t)i + 1];
    float pz = xyz[3 * (size_t)i + 2];

    float f[NF];

    // plane 0: (u=x, v=y)   plane 1: (u=x, v=z)   plane 2: (u=y, v=z)
    float us[3] = {px, px, py};
    float vs[3] = {py, pz, pz};

#pragma unroll
    for (int p = 0; p < 3; ++p) {
        float x = us[p] * (float)(RES - 1);
        float y = vs[p] * (float)(RES - 1);
        x = fminf(fmaxf(x, 0.0f), (float)(RES - 1));
        y = fminf(fmaxf(y, 0.0f), (float)(RES - 1));
        int x0 = (int)x;            // x >= 0 so trunc == floor
        int y0 = (int)y;
        int x1 = min(x0 + 1, RES - 1);
        int y1 = min(y0 + 1, RES - 1);
        float wx = x - (float)x0;
        float wy = y - (float)y0;
        float w00 = (1.0f - wx) * (1.0f - wy);
        float w01 = wx * (1.0f - wy);
        float w10 = (1.0f - wx) * wy;
        float w11 = wx * wy;

        if (TR) {
            const float* base = tp + (size_t)p * NHW * RANK;
            const float4* t00 = (const float4*)(base + (size_t)(y0 * RES + x0) * RANK);
            const float4* t01 = (const float4*)(base + (size_t)(y0 * RES + x1) * RANK);
            const float4* t10 = (const float4*)(base + (size_t)(y1 * RES + x0) * RANK);
            const float4* t11 = (const float4*)(base + (size_t)(y1 * RES + x1) * RANK);
#pragma unroll
            for (int q = 0; q < 3; ++q) {
                float4 a = t00[q];
                float4 b = t01[q];
                float4 c = t10[q];
                float4 d = t11[q];
                f[p * RANK + 4 * q + 0] = w00 * a.x + w01 * b.x + w10 * c.x + w11 * d.x;
                f[p * RANK + 4 * q + 1] = w00 * a.y + w01 * b.y + w10 * c.y + w11 * d.y;
                f[p * RANK + 4 * q + 2] = w00 * a.z + w01 * b.z + w10 * c.z + w11 * d.z;
                f[p * RANK + 4 * q + 3] = w00 * a.w + w01 * b.w + w10 * c.w + w11 * d.w;
            }
        } else {
            const float* base = (p == 0) ? pa : (p == 1) ? pb : pc;
            int i00 = y0 * RES + x0;
            int i01 = y0 * RES + x1;
            int i10 = y1 * RES + x0;
            int i11 = y1 * RES + x1;
#pragma unroll
            for (int r = 0; r < RANK; ++r) {
                const float* pr = base + (size_t)r * NHW;
                f[p * RANK + r] = w00 * pr[i00] + w01 * pr[i01] + w10 * pr[i10] + w11 * pr[i11];
            }
        }
    }

    // Dense layer: out[o] = sum_k f[k] * w[o*NF + k].
    // w accesses are wave-uniform at constant offsets -> compiler emits
    // s_load_dwordx16 + v_fmac with SGPR operand (no LDS round-trip).
    float acc[ODIM];
#pragma unroll
    for (int o = 0; o < ODIM; ++o) {
        float s = 0.0f;
#pragma unroll
        for (int k = 0; k < NF; ++k) s += f[k] * w[o * NF + k];
        acc[o] = s;
    }

    float4* op = (float4*)(out + (size_t)i * ODIM);
#pragma unroll
    for (int q = 0; q < 8; ++q) {
        op[q] = make_float4(acc[4 * q + 0], acc[4 * q + 1], acc[4 * q + 2], acc[4 * q + 3]);
    }
}

extern "C" void kernel_launch(void* const* d_in, const int* in_sizes, int n_in,
                              void* d_out, int out_size, void* d_ws, size_t ws_size,
                              hipStream_t stream) {
    const float* xyz = (const float*)d_in[0];
    const float* xy  = (const float*)d_in[1];
    const float* xz  = (const float*)d_in[2];
    const float* yz  = (const float*)d_in[3];
    const float* wml = (const float*)d_in[4];
    float* out = (float*)d_out;

    int n = in_sizes[0] / 3;

    const size_t tbytes = (size_t)3 * NHW * RANK * sizeof(float);
    bool use_tr = (ws_size >= tbytes) && (d_ws != nullptr);

    int nblk = (n + 255) / 256;

    if (use_tr) {
        float* tp = (float*)d_ws;
        int tblk = (3 * NHW + 255) / 256;
        vme_transpose<<<tblk, 256, 0, stream>>>(xy, xz, yz, tp);
        vme_main<true><<<nblk, 256, 0, stream>>>(xyz, xy, xz, yz, tp, wml, out, n);
    } else {
        vme_main<false><<<nblk, 256, 0, stream>>>(xyz, xy, xz, yz, nullptr, wml, out, n);
    }
}